// Round 12
// baseline (217.456 us; speedup 1.0000x reference)
//
#include <hip/hip_runtime.h>

typedef __attribute__((ext_vector_type(8))) short bf16x8;
typedef __attribute__((ext_vector_type(4))) float f32x4;
typedef unsigned int uint;
typedef unsigned short ushort;

#define NFEAT 128

__device__ __forceinline__ ushort f2b(float f) {
    uint u = __float_as_uint(f);
    u = (u + 0x7fffu + ((u >> 16) & 1u)) >> 16;   // RNE
    return (ushort)u;
}

// async global->LDS, 16B per lane; lds base must be wave-uniform (HW adds lane*16)
__device__ __forceinline__ void gload_lds16(const ushort* g, char* lds) {
    __builtin_amdgcn_global_load_lds((const __attribute__((address_space(1))) void*)g,
                                     (__attribute__((address_space(3))) void*)lds, 16, 0, 0);
}

// ---------------- zero deg + scan state (replaces runtime fillBuffer) ----------------
__global__ __launch_bounds__(256) void zero_kernel(int* __restrict__ p, int n4) {
    const int i = blockIdx.x * 256 + threadIdx.x;
    if (i < n4) *(int4*)(p + i * 4) = make_int4(0, 0, 0, 0);
}

// ---------------- merged prep: x->bf16 convert | weight prep | degree histogram ----
__global__ __launch_bounds__(256) void prep(
    const float* __restrict__ x, ushort* __restrict__ x_bf, long nx,
    const float* __restrict__ w1l, const float* __restrict__ w1r,
    const float* __restrict__ w2l, const float* __restrict__ w2r,
    const float* __restrict__ wd,
    ushort* __restrict__ wc1, ushort* __restrict__ wc2, ushort* __restrict__ wdec,
    const int* __restrict__ dst, int* __restrict__ deg, int E, int nCvt)
{
    const int b = blockIdx.x;
    if (b < nCvt) {
        long i = ((long)b * 256 + threadIdx.x) * 4;
        if (i < nx) {
            float4 v = *(const float4*)(x + i);
            ushort4 o;
            o.x = f2b(v.x); o.y = f2b(v.y); o.z = f2b(v.z); o.w = f2b(v.w);
            *(ushort4*)(x_bf + i) = o;
        }
    } else if (b < nCvt + 256) {
        const int bb = b - nCvt;
        const int i = (bb & 127) * 256 + threadIdx.x;
        const int row = i >> 8, col = i & 255;
        const float* wl = (bb < 128) ? w1l : w2l;
        const float* wr = (bb < 128) ? w1r : w2r;
        ushort* dstw = (bb < 128) ? wc1 : wc2;
        float v = (col < 128) ? wl[row * 128 + col] : wr[row * 128 + col - 128];
        dstw[i] = f2b(v);
    } else if (b < nCvt + 320) {
        const int i = (b - nCvt - 256) * 256 + threadIdx.x;   // 64*256 = 16384
        wdec[i] = f2b(wd[i]);
    } else {
        const int e = (b - nCvt - 320) * 256 + threadIdx.x;
        if (e < E) atomicAdd(&deg[dst[e]], 1);
    }
}

// ---------------- single-pass exclusive scan (decoupled lookback, nb<=512 blocks) ----
// state[b] = (value<<2) | flag; flag: 0=empty, 1=aggregate, 2=inclusive-prefix.
// All nb blocks are co-resident (nb=98) -> lookback spin cannot deadlock.
__global__ __launch_bounds__(256) void scan_lookback(
    const int* __restrict__ deg, int* __restrict__ row_off, int* __restrict__ pos,
    int* __restrict__ state, int n, int E)
{
    __shared__ int lds[256];
    __shared__ int sExcl;
    const int b = blockIdx.x, t = threadIdx.x;
    const int base = b * 1024 + t * 4;
    int a[4];
#pragma unroll
    for (int q = 0; q < 4; ++q) a[q] = (base + q < n) ? deg[base + q] : 0;
    const int tsum = a[0] + a[1] + a[2] + a[3];
    lds[t] = tsum;
    __syncthreads();
    for (int off = 1; off < 256; off <<= 1) {
        int v = (t >= off) ? lds[t - off] : 0;
        __syncthreads();
        lds[t] += v;
        __syncthreads();
    }
    const int texcl = lds[t] - tsum;        // thread-local exclusive prefix
    const int total = lds[255];             // block total
    if (t == 0) {
        if (b == 0) {
            __hip_atomic_store(&state[0], (total << 2) | 2, __ATOMIC_RELEASE, __HIP_MEMORY_SCOPE_AGENT);
            sExcl = 0;
        } else {
            __hip_atomic_store(&state[b], (total << 2) | 1, __ATOMIC_RELEASE, __HIP_MEMORY_SCOPE_AGENT);
            int ex = 0;
            for (int j = b - 1; j >= 0; --j) {
                int s;
                do {
                    s = __hip_atomic_load(&state[j], __ATOMIC_ACQUIRE, __HIP_MEMORY_SCOPE_AGENT);
                } while ((s & 3) == 0);
                ex += s >> 2;
                if ((s & 3) == 2) break;
            }
            __hip_atomic_store(&state[b], ((ex + total) << 2) | 2, __ATOMIC_RELEASE, __HIP_MEMORY_SCOPE_AGENT);
            sExcl = ex;
        }
    }
    __syncthreads();
    int r = sExcl + texcl;
#pragma unroll
    for (int q = 0; q < 4; ++q) {
        if (base + q < n) { row_off[base + q] = r; pos[base + q] = r; }
        r += a[q];
    }
    if (b == 0 && t == 0) row_off[n] = E;
}

// ---------------- CSR bucket fill ----------------
__global__ void fill_csr(const int* __restrict__ src, const int* __restrict__ dst,
                         int* __restrict__ pos, int* __restrict__ perm, int E) {
    const int e = blockIdx.x * blockDim.x + threadIdx.x;
    if (e < E) {
        const int p = atomicAdd(&pos[dst[e]], 1);
        perm[p] = src[e];
    }
}

// ---------------- gather mean: 16-lane group per node, always-8-wide masked -------
// 8 independent row-loads in flight per group -> one latency round-trip for 84% of
// nodes (deg ~ Poisson(6)).
__global__ __launch_bounds__(256) void gather_mean_bf(const int* __restrict__ row_off,
                                                      const int* __restrict__ perm,
                                                      const ushort* __restrict__ feat,
                                                      ushort* __restrict__ out, int n) {
    const int node = (blockIdx.x * 256 + threadIdx.x) >> 4;
    if (node >= n) return;
    const int chunk = threadIdx.x & 15;
    const ushort* fp = feat + chunk * 8;
    const int lo = row_off[node], hi = row_off[node + 1];
    float acc[8] = {0.f, 0.f, 0.f, 0.f, 0.f, 0.f, 0.f, 0.f};
    const uint4 z = make_uint4(0, 0, 0, 0);
    for (int i = lo; i < hi; i += 8) {
        int idx[8];
#pragma unroll
        for (int k = 0; k < 8; ++k) idx[k] = perm[(i + k < hi) ? i + k : i];
        uint4 v[8];
#pragma unroll
        for (int k = 0; k < 8; ++k) v[k] = *(const uint4*)(fp + (size_t)idx[k] * NFEAT);
#pragma unroll
        for (int k = 0; k < 8; ++k) if (i + k >= hi) v[k] = z;
#pragma unroll
        for (int k = 0; k < 8; ++k) {
            const uint p[4] = {v[k].x, v[k].y, v[k].z, v[k].w};
#pragma unroll
            for (int q = 0; q < 4; ++q) {
                acc[2 * q]     += __uint_as_float(p[q] << 16);
                acc[2 * q + 1] += __uint_as_float(p[q] & 0xffff0000u);
            }
        }
    }
    const float inv = 1.0f / fmaxf((float)(hi - lo), 1.0f);
    ushort o[8] __attribute__((aligned(16)));
#pragma unroll
    for (int q = 0; q < 8; ++q) o[q] = f2b(acc[q] * inv);
    *(uint4*)(out + (size_t)node * NFEAT + chunk * 8) = *(const uint4*)o;
}

// ---------------- bf16 MFMA GEMM, BM=64 tile (staged via global_load_lds) + decoder -
// out[row][col] = sum_k A[row][k] * Wcat[col][k] + bias[col]   (A = [mean|xin], K=256)
// Staging: global_load_lds width=16, linear LDS dest, XOR-swizzle on the GLOBAL
// source chunk (c ^ (row&7)), swizzled ds_read (both-sides rule).
// Swapped MFMA operands: C layout row=lane&15 (node row), col=(lane>>4)*4+reg.
template <bool RELU, bool DEC>
__global__ __launch_bounds__(256) void sage_mfma(
    const ushort* __restrict__ Amean, const ushort* __restrict__ Axin,
    const ushort* __restrict__ Wcat, const float* __restrict__ bias,
    const ushort* __restrict__ Wdec, const float* __restrict__ bdec,
    float* __restrict__ outf, ushort* __restrict__ outb,
    float* __restrict__ dxp, int n)
{
    __shared__ uint4 smem4[1536];            // 24 KiB: As 8KB + Ws 16KB
    char* As = (char*)smem4;                 // [64 rows][128B] swizzled
    char* Ws = As + 8192;                    // [128 cols][128B] swizzled
    const int t = threadIdx.x;
    const int m0 = blockIdx.x * 64;
    const int lane = t & 63;
    const int wid = t >> 6;
    const int lrow = lane & 15;
    const int lq = lane >> 4;

    f32x4 acc[8];
#pragma unroll
    for (int nn = 0; nn < 8; ++nn) acc[nn] = (f32x4){0.f, 0.f, 0.f, 0.f};

    for (int kt = 0; kt < 4; ++kt) {
        const ushort* Abase = (kt < 2) ? Amean : Axin;
        const int co = (kt & 1) * 64;
#pragma unroll
        for (int i = 0; i < 2; ++i) {
            const int row = i * 32 + wid * 8 + (lane >> 3);
            const int c = (lane & 7) ^ (row & 7);            // pre-swizzled source chunk
            int gm = m0 + row;
            if (gm >= n) gm = n - 1;                         // clamp; masked at epilogue
            gload_lds16(Abase + (size_t)gm * NFEAT + co + c * 8,
                        As + i * 4096 + wid * 1024);
        }
#pragma unroll
        for (int i = 0; i < 4; ++i) {
            const int row = i * 32 + wid * 8 + (lane >> 3);
            const int c = (lane & 7) ^ (row & 7);
            gload_lds16(Wcat + (size_t)row * 256 + kt * 64 + c * 8,
                        Ws + i * 4096 + wid * 1024);
        }
        __syncthreads();
#pragma unroll
        for (int ks = 0; ks < 2; ++ks) {
            bf16x8 af, bfr[8];
            {
                const int row = wid * 16 + lrow;
                af = *(const bf16x8*)(As + row * 128 + (((ks * 4 + lq) * 16) ^ ((row & 7) << 4)));
            }
#pragma unroll
            for (int nn = 0; nn < 8; ++nn) {
                const int row = nn * 16 + lrow;
                bfr[nn] = *(const bf16x8*)(Ws + row * 128 + (((ks * 4 + lq) * 16) ^ ((row & 7) << 4)));
            }
#pragma unroll
            for (int nn = 0; nn < 8; ++nn)
                acc[nn] = __builtin_amdgcn_mfma_f32_16x16x32_bf16(bfr[nn], af, acc[nn], 0, 0, 0);
        }
        __syncthreads();   // also gates the DEC Lh overwrite after the last kt
    }

    // ---- h epilogue (swapped C layout): node row = lane&15, cols = lq*4 + reg
    char* Lh = As;   // DEC: [64 rows][256B] swizzled, wave-private 4KB quarters
    const int row = wid * 16 + lrow;
    const int grow = m0 + row;
#pragma unroll
    for (int nn = 0; nn < 8; ++nn) {
        const int colb = nn * 16 + lq * 4;
        const float4 bv = *(const float4*)(bias + colb);
        float v0 = acc[nn][0] + bv.x;
        float v1 = acc[nn][1] + bv.y;
        float v2 = acc[nn][2] + bv.z;
        float v3 = acc[nn][3] + bv.w;
        if (RELU) {
            v0 = fmaxf(v0, 0.f); v1 = fmaxf(v1, 0.f);
            v2 = fmaxf(v2, 0.f); v3 = fmaxf(v3, 0.f);
        }
        ushort4 ob;
        ob.x = f2b(v0); ob.y = f2b(v1); ob.z = f2b(v2); ob.w = f2b(v3);
        if (grow < n) {
            if (outf) *(float4*)(outf + (size_t)grow * NFEAT + colb) = make_float4(v0, v1, v2, v3);
            if (outb) *(ushort4*)(outb + (size_t)grow * NFEAT + colb) = ob;
        }
        if (DEC)
            *(ushort4*)(Lh + row * 256 + ((colb * 2) ^ ((row & 7) << 4))) = ob;
    }
    if (DEC) {
        // wave-private quarter: same wave writes and reads its own 16 rows
        f32x4 acc2[8];
#pragma unroll
        for (int nn = 0; nn < 8; ++nn) acc2[nn] = (f32x4){0.f, 0.f, 0.f, 0.f};
#pragma unroll
        for (int ks = 0; ks < 4; ++ks) {
            bf16x8 af2, bf2[8];
            af2 = *(const bf16x8*)(Lh + row * 256 + ((ks * 64 + lq * 16) ^ ((row & 7) << 4)));
#pragma unroll
            for (int nn = 0; nn < 8; ++nn)
                bf2[nn] = *(const bf16x8*)(Wdec + (size_t)(nn * 16 + lrow) * NFEAT + ks * 32 + lq * 8);
#pragma unroll
            for (int nn = 0; nn < 8; ++nn)
                acc2[nn] = __builtin_amdgcn_mfma_f32_16x16x32_bf16(bf2[nn], af2, acc2[nn], 0, 0, 0);
        }
        if (grow < n) {
#pragma unroll
            for (int nn = 0; nn < 8; ++nn) {
                const int colb = nn * 16 + lq * 4;
                const float4 bv = *(const float4*)(bdec + colb);
                *(float4*)(dxp + (size_t)grow * NFEAT + colb) =
                    make_float4(acc2[nn][0] + bv.x, acc2[nn][1] + bv.y,
                                acc2[nn][2] + bv.z, acc2[nn][3] + bv.w);
            }
        }
    }
}

extern "C" void kernel_launch(void* const* d_in, const int* in_sizes, int n_in,
                              void* d_out, int out_size, void* d_ws, size_t ws_size,
                              hipStream_t stream) {
    const float* x     = (const float*)d_in[0];
    const int*   xedge = (const int*)d_in[1];
    const float* w1_l  = (const float*)d_in[2];
    const float* b1_l  = (const float*)d_in[3];
    const float* w1_r  = (const float*)d_in[4];
    const float* w2_l  = (const float*)d_in[5];
    const float* b2_l  = (const float*)d_in[6];
    const float* w2_r  = (const float*)d_in[7];
    const float* w_dec = (const float*)d_in[8];
    const float* b_dec = (const float*)d_in[9];

    const int N = in_sizes[0] / NFEAT;
    const int E = in_sizes[1] / 2;
    const int* src = xedge;
    const int* dst = xedge + E;

    float* h_out = (float*)d_out;                 // output 0: h  [N,128] fp32
    float* dxp   = h_out + (size_t)N * NFEAT;     // output 1: dx [N,128] fp32

    // ws: x_bf | h1_bf | mean_bf | wc1 | wc2 | wdec | deg | row_off | pos | state | perm
    char* ws = (char*)d_ws;
    ushort* x_bf    = (ushort*)ws;
    ushort* h1_bf   = x_bf   + (size_t)N * NFEAT;
    ushort* mean_bf = h1_bf  + (size_t)N * NFEAT;
    ushort* wc1     = mean_bf + (size_t)N * NFEAT;
    ushort* wc2     = wc1 + 128 * 256;
    ushort* wdec    = wc2 + 128 * 256;
    int* deg        = (int*)(wdec + 128 * 128);   // 256B-aligned by construction
    int* row_off    = deg + N;
    int* pos        = row_off + (N + 1);
    int* state      = pos + N;                    // 512 ints (zeroed with deg)
    int* perm       = state + 512;

    const int nb = (N + 1023) / 1024;             // 98 scan blocks (state sized 512)

    // ---- zero deg + scan state (our own kernel; replaces runtime fill path) ----
    // deg..state span N + (N+1) + N + 512 ints? only deg[N] and state[512] need zero:
    // deg is first, state sits after pos; zero them in one launch via two ranges.
    {
        const int degi4 = (N + 3) / 4;            // int4 count for deg
        const int sti4  = 512 / 4;
        zero_kernel<<<(degi4 + 255) / 256, 256, 0, stream>>>(deg, degi4);
        zero_kernel<<<(sti4 + 255) / 256, 256, 0, stream>>>(state, sti4);
    }

    const long nx = (long)N * NFEAT;
    const int nCvt = (int)((nx / 4 + 255) / 256);
    const int histB = (E + 255) / 256;
    prep<<<nCvt + 320 + histB, 256, 0, stream>>>(x, x_bf, nx, w1_l, w1_r, w2_l, w2_r, w_dec,
                                                 wc1, wc2, wdec, dst, deg, E, nCvt);

    // ---- CSR build: single-pass scan + bucket fill ----
    scan_lookback<<<nb, 256, 0, stream>>>(deg, row_off, pos, state, N, E);
    fill_csr<<<histB, 256, 0, stream>>>(src, dst, pos, perm, E);

    const int gb = (N + 63) / 64;
    const int ggb = (N * 16 + 255) / 256;

    // ---- layer 1 ----
    gather_mean_bf<<<ggb, 256, 0, stream>>>(row_off, perm, x_bf, mean_bf, N);
    sage_mfma<true, false><<<gb, 256, 0, stream>>>(mean_bf, x_bf, wc1, b1_l,
                                                   nullptr, nullptr, nullptr, h1_bf, nullptr, N);

    // ---- layer 2 + fused decoder ----
    gather_mean_bf<<<ggb, 256, 0, stream>>>(row_off, perm, h1_bf, mean_bf, N);
    sage_mfma<false, true><<<gb, 256, 0, stream>>>(mean_bf, h1_bf, wc2, b2_l,
                                                   wdec, b_dec, h_out, nullptr, dxp, N);

    (void)n_in; (void)out_size; (void)ws_size;
}

// Round 13
// 199.753 us; speedup vs baseline: 1.0886x; 1.0886x over previous
//
#include <hip/hip_runtime.h>

typedef __attribute__((ext_vector_type(8))) short bf16x8;
typedef __attribute__((ext_vector_type(4))) float f32x4;
typedef unsigned int uint;
typedef unsigned short ushort;

#define NFEAT 128

__device__ __forceinline__ ushort f2b(float f) {
    uint u = __float_as_uint(f);
    u = (u + 0x7fffu + ((u >> 16) & 1u)) >> 16;   // RNE
    return (ushort)u;
}

// async global->LDS, 16B per lane; lds base must be wave-uniform (HW adds lane*16)
__device__ __forceinline__ void gload_lds16(const ushort* g, char* lds) {
    __builtin_amdgcn_global_load_lds((const __attribute__((address_space(1))) void*)g,
                                     (__attribute__((address_space(3))) void*)lds, 16, 0, 0);
}

// ---------------- merged prep: x->bf16 convert | weight prep | degree histogram ----
__global__ __launch_bounds__(256) void prep(
    const float* __restrict__ x, ushort* __restrict__ x_bf, long nx,
    const float* __restrict__ w1l, const float* __restrict__ w1r,
    const float* __restrict__ w2l, const float* __restrict__ w2r,
    const float* __restrict__ wd,
    ushort* __restrict__ wc1, ushort* __restrict__ wc2, ushort* __restrict__ wdec,
    const int* __restrict__ dst, int* __restrict__ deg, int E, int nCvt)
{
    const int b = blockIdx.x;
    if (b < nCvt) {
        long i = ((long)b * 256 + threadIdx.x) * 4;
        if (i < nx) {
            float4 v = *(const float4*)(x + i);
            ushort4 o;
            o.x = f2b(v.x); o.y = f2b(v.y); o.z = f2b(v.z); o.w = f2b(v.w);
            *(ushort4*)(x_bf + i) = o;
        }
    } else if (b < nCvt + 256) {
        const int bb = b - nCvt;
        const int i = (bb & 127) * 256 + threadIdx.x;
        const int row = i >> 8, col = i & 255;
        const float* wl = (bb < 128) ? w1l : w2l;
        const float* wr = (bb < 128) ? w1r : w2r;
        ushort* dstw = (bb < 128) ? wc1 : wc2;
        float v = (col < 128) ? wl[row * 128 + col] : wr[row * 128 + col - 128];
        dstw[i] = f2b(v);
    } else if (b < nCvt + 320) {
        const int i = (b - nCvt - 256) * 256 + threadIdx.x;   // 64*256 = 16384
        wdec[i] = f2b(wd[i]);
    } else {
        const int e = (b - nCvt - 320) * 256 + threadIdx.x;
        if (e < E) atomicAdd(&deg[dst[e]], 1);
    }
}

// ---------------- exclusive scan: block-local pass ----------------
__global__ __launch_bounds__(256) void scan_blocks(const int* __restrict__ in, int* __restrict__ out,
                                                   int* __restrict__ bsum, int n) {
    __shared__ int lds[256];
    const int t = threadIdx.x;
    const int base = blockIdx.x * 1024 + t * 4;
    int a[4];
#pragma unroll
    for (int q = 0; q < 4; ++q) a[q] = (base + q < n) ? in[base + q] : 0;
    const int tsum = a[0] + a[1] + a[2] + a[3];
    lds[t] = tsum;
    __syncthreads();
    for (int off = 1; off < 256; off <<= 1) {
        int v = (t >= off) ? lds[t - off] : 0;
        __syncthreads();
        lds[t] += v;
        __syncthreads();
    }
    const int excl = lds[t] - tsum;
    if (t == 255) bsum[blockIdx.x] = lds[255];
    int r = excl;
#pragma unroll
    for (int q = 0; q < 4; ++q) {
        if (base + q < n) out[base + q] = r;
        r += a[q];
    }
}

// ---------------- scan finalize: inline carry (wave all-reduce over bsum prefix) ----
__global__ __launch_bounds__(256) void scan_add(int* __restrict__ row_off, int* __restrict__ pos,
                                                const int* __restrict__ bsum, int n, int E) {
    const int i = blockIdx.x * 256 + threadIdx.x;
    const int cb = blockIdx.x >> 2;
    const int lane = threadIdx.x & 63;
    int v = 0;
    if (lane < cb) v += bsum[lane];
    if (lane + 64 < cb) v += bsum[lane + 64];
#pragma unroll
    for (int off = 1; off < 64; off <<= 1) v += __shfl_xor(v, off);
    if (i < n) {
        const int r = row_off[i] + v;
        row_off[i] = r;
        pos[i] = r;
    }
    if (i == 0) row_off[n] = E;
}

// ---------------- CSR bucket fill ----------------
__global__ void fill_csr(const int* __restrict__ src, const int* __restrict__ dst,
                         int* __restrict__ pos, int* __restrict__ perm, int E) {
    const int e = blockIdx.x * blockDim.x + threadIdx.x;
    if (e < E) {
        const int p = atomicAdd(&pos[dst[e]], 1);
        perm[p] = src[e];
    }
}

// ---------------- gather mean: one 16-lane group per node, 4-deep unroll ----------
__global__ __launch_bounds__(256) void gather_mean_bf(const int* __restrict__ row_off,
                                                      const int* __restrict__ perm,
                                                      const ushort* __restrict__ feat,
                                                      ushort* __restrict__ out, int n) {
    const int node = (blockIdx.x * 256 + threadIdx.x) >> 4;
    if (node >= n) return;
    const int chunk = threadIdx.x & 15;
    const int lo = row_off[node], hi = row_off[node + 1];
    float acc[8] = {0.f, 0.f, 0.f, 0.f, 0.f, 0.f, 0.f, 0.f};
    int i = lo;
    for (; i + 3 < hi; i += 4) {
        const int s0 = perm[i], s1 = perm[i + 1], s2 = perm[i + 2], s3 = perm[i + 3];
        const uint4 v0 = *(const uint4*)(feat + (size_t)s0 * NFEAT + chunk * 8);
        const uint4 v1 = *(const uint4*)(feat + (size_t)s1 * NFEAT + chunk * 8);
        const uint4 v2 = *(const uint4*)(feat + (size_t)s2 * NFEAT + chunk * 8);
        const uint4 v3 = *(const uint4*)(feat + (size_t)s3 * NFEAT + chunk * 8);
        const uint p0[4] = {v0.x, v0.y, v0.z, v0.w};
        const uint p1[4] = {v1.x, v1.y, v1.z, v1.w};
        const uint p2[4] = {v2.x, v2.y, v2.z, v2.w};
        const uint p3[4] = {v3.x, v3.y, v3.z, v3.w};
#pragma unroll
        for (int q = 0; q < 4; ++q) {
            acc[2 * q]     += __uint_as_float(p0[q] << 16) + __uint_as_float(p1[q] << 16)
                            + __uint_as_float(p2[q] << 16) + __uint_as_float(p3[q] << 16);
            acc[2 * q + 1] += __uint_as_float(p0[q] & 0xffff0000u) + __uint_as_float(p1[q] & 0xffff0000u)
                            + __uint_as_float(p2[q] & 0xffff0000u) + __uint_as_float(p3[q] & 0xffff0000u);
        }
    }
    for (; i < hi; ++i) {
        const int s = perm[i];
        const uint4 v = *(const uint4*)(feat + (size_t)s * NFEAT + chunk * 8);
        const uint p[4] = {v.x, v.y, v.z, v.w};
#pragma unroll
        for (int q = 0; q < 4; ++q) {
            acc[2 * q]     += __uint_as_float(p[q] << 16);
            acc[2 * q + 1] += __uint_as_float(p[q] & 0xffff0000u);
        }
    }
    const float inv = 1.0f / fmaxf((float)(hi - lo), 1.0f);
    ushort o[8] __attribute__((aligned(16)));
#pragma unroll
    for (int q = 0; q < 8; ++q) o[q] = f2b(acc[q] * inv);
    *(uint4*)(out + (size_t)node * NFEAT + chunk * 8) = *(const uint4*)o;
}

// ---------------- bf16 MFMA GEMM (staged via global_load_lds) + optional decoder ----
// out[row][col] = sum_k A[row][k] * Wcat[col][k] + bias[col]   (A = [mean|xin], K=256)
// Staging: global_load_lds width=16, LINEAR LDS dest (wave base + lane*16), the
// XOR-swizzle applied to the GLOBAL source chunk index (c = pc ^ (row&7)) so the
// swizzled ds_read side is unchanged (rule: both-sides-or-neither).
// Swapped MFMA operands: C layout row=lane&15 (node row), col=(lane>>4)*4+reg.
template <bool RELU, bool DEC>
__global__ __launch_bounds__(256) void sage_mfma(
    const ushort* __restrict__ Amean, const ushort* __restrict__ Axin,
    const ushort* __restrict__ Wcat, const float* __restrict__ bias,
    const ushort* __restrict__ Wdec, const float* __restrict__ bdec,
    float* __restrict__ outf, ushort* __restrict__ outb,
    float* __restrict__ dxp, int n)
{
    __shared__ uint4 smem4[2048];            // 32 KiB
    char* As = (char*)smem4;                 // [128 rows][64 bf16] swizzled
    char* Ws = As + 16384;
    const int t = threadIdx.x;
    const int m0 = blockIdx.x * 128;
    const int lane = t & 63;
    const int wid = t >> 6;
    const int lrow = lane & 15;
    const int lq = lane >> 4;

    f32x4 acc[2][8];
#pragma unroll
    for (int m = 0; m < 2; ++m)
#pragma unroll
        for (int nn = 0; nn < 8; ++nn) acc[m][nn] = (f32x4){0.f, 0.f, 0.f, 0.f};

    for (int kt = 0; kt < 4; ++kt) {
        const ushort* Abase = (kt < 2) ? Amean : Axin;
        const int co = (kt & 1) * 64;
        // ---- stage A and W tiles: 4 x 1KB wave-uniform chunks each
#pragma unroll
        for (int i = 0; i < 4; ++i) {
            const int row = i * 32 + wid * 8 + (lane >> 3);  // this lane's dest row
            const int c = (lane & 7) ^ (row & 7);            // pre-swizzled source chunk
            int gm = m0 + row;
            if (gm >= n) gm = n - 1;                         // clamp; masked at epilogue
            gload_lds16(Abase + (size_t)gm * NFEAT + co + c * 8,
                        As + i * 4096 + wid * 1024);
            gload_lds16(Wcat + (size_t)row * 256 + kt * 64 + c * 8,
                        Ws + i * 4096 + wid * 1024);
        }
        __syncthreads();
#pragma unroll
        for (int ks = 0; ks < 2; ++ks) {
            bf16x8 af[2], bfr[8];
#pragma unroll
            for (int m = 0; m < 2; ++m) {
                const int row = wid * 32 + m * 16 + lrow;
                af[m] = *(const bf16x8*)(As + row * 128 + (((ks * 4 + lq) * 16) ^ ((row & 7) << 4)));
            }
#pragma unroll
            for (int nn = 0; nn < 8; ++nn) {
                const int row = nn * 16 + lrow;
                bfr[nn] = *(const bf16x8*)(Ws + row * 128 + (((ks * 4 + lq) * 16) ^ ((row & 7) << 4)));
            }
#pragma unroll
            for (int m = 0; m < 2; ++m)
#pragma unroll
                for (int nn = 0; nn < 8; ++nn)
                    acc[m][nn] = __builtin_amdgcn_mfma_f32_16x16x32_bf16(bfr[nn], af[m], acc[m][nn], 0, 0, 0);
        }
        __syncthreads();
    }
    // ---- h epilogue (swapped C layout): node row = lane&15, cols = lq*4 + r
    char* Lh = As;   // DEC: [128 rows][128 bf16] swizzled, wave-private quarters
#pragma unroll
    for (int m = 0; m < 2; ++m) {
        const int row = wid * 32 + m * 16 + lrow;
        const int grow = m0 + row;
#pragma unroll
        for (int nn = 0; nn < 8; ++nn) {
            const int colb = nn * 16 + lq * 4;
            const float4 bv = *(const float4*)(bias + colb);
            float v0 = acc[m][nn][0] + bv.x;
            float v1 = acc[m][nn][1] + bv.y;
            float v2 = acc[m][nn][2] + bv.z;
            float v3 = acc[m][nn][3] + bv.w;
            if (RELU) {
                v0 = fmaxf(v0, 0.f); v1 = fmaxf(v1, 0.f);
                v2 = fmaxf(v2, 0.f); v3 = fmaxf(v3, 0.f);
            }
            ushort4 ob;
            ob.x = f2b(v0); ob.y = f2b(v1); ob.z = f2b(v2); ob.w = f2b(v3);
            if (grow < n) {
                if (outf) *(float4*)(outf + (size_t)grow * NFEAT + colb) = make_float4(v0, v1, v2, v3);
                if (outb) *(ushort4*)(outb + (size_t)grow * NFEAT + colb) = ob;
            }
            if (DEC)
                *(ushort4*)(Lh + row * 256 + ((colb * 2) ^ ((row & 7) << 4))) = ob;
        }
    }
    if (DEC) {
        // wave-private quarters: no barrier needed
        f32x4 acc2[2][8];
#pragma unroll
        for (int m = 0; m < 2; ++m)
#pragma unroll
            for (int nn = 0; nn < 8; ++nn) acc2[m][nn] = (f32x4){0.f, 0.f, 0.f, 0.f};
#pragma unroll
        for (int ks = 0; ks < 4; ++ks) {
            bf16x8 af2[2], bf2[8];
#pragma unroll
            for (int m = 0; m < 2; ++m) {
                const int row = wid * 32 + m * 16 + lrow;
                af2[m] = *(const bf16x8*)(Lh + row * 256 + ((ks * 64 + lq * 16) ^ ((row & 7) << 4)));
            }
#pragma unroll
            for (int nn = 0; nn < 8; ++nn)
                bf2[nn] = *(const bf16x8*)(Wdec + (size_t)(nn * 16 + lrow) * NFEAT + ks * 32 + lq * 8);
#pragma unroll
            for (int m = 0; m < 2; ++m)
#pragma unroll
                for (int nn = 0; nn < 8; ++nn)
                    acc2[m][nn] = __builtin_amdgcn_mfma_f32_16x16x32_bf16(bf2[nn], af2[m], acc2[m][nn], 0, 0, 0);
        }
#pragma unroll
        for (int m = 0; m < 2; ++m) {
            const int grow = m0 + wid * 32 + m * 16 + lrow;
            if (grow < n) {
#pragma unroll
                for (int nn = 0; nn < 8; ++nn) {
                    const int colb = nn * 16 + lq * 4;
                    const float4 bv = *(const float4*)(bdec + colb);
                    *(float4*)(dxp + (size_t)grow * NFEAT + colb) =
                        make_float4(acc2[m][nn][0] + bv.x, acc2[m][nn][1] + bv.y,
                                    acc2[m][nn][2] + bv.z, acc2[m][nn][3] + bv.w);
                }
            }
        }
    }
}

extern "C" void kernel_launch(void* const* d_in, const int* in_sizes, int n_in,
                              void* d_out, int out_size, void* d_ws, size_t ws_size,
                              hipStream_t stream) {
    const float* x     = (const float*)d_in[0];
    const int*   xedge = (const int*)d_in[1];
    const float* w1_l  = (const float*)d_in[2];
    const float* b1_l  = (const float*)d_in[3];
    const float* w1_r  = (const float*)d_in[4];
    const float* w2_l  = (const float*)d_in[5];
    const float* b2_l  = (const float*)d_in[6];
    const float* w2_r  = (const float*)d_in[7];
    const float* w_dec = (const float*)d_in[8];
    const float* b_dec = (const float*)d_in[9];

    const int N = in_sizes[0] / NFEAT;
    const int E = in_sizes[1] / 2;
    const int* src = xedge;
    const int* dst = xedge + E;

    float* h_out = (float*)d_out;                 // output 0: h  [N,128] fp32
    float* dxp   = h_out + (size_t)N * NFEAT;     // output 1: dx [N,128] fp32

    // ws: x_bf | h1_bf | mean_bf | wc1 | wc2 | wdec | deg | row_off | pos | bsum | perm
    char* ws = (char*)d_ws;
    ushort* x_bf    = (ushort*)ws;
    ushort* h1_bf   = x_bf   + (size_t)N * NFEAT;
    ushort* mean_bf = h1_bf  + (size_t)N * NFEAT;
    ushort* wc1     = mean_bf + (size_t)N * NFEAT;
    ushort* wc2     = wc1 + 128 * 256;
    ushort* wdec    = wc2 + 128 * 256;
    int* deg        = (int*)(wdec + 128 * 128);
    int* row_off    = deg + N;
    int* pos        = row_off + (N + 1);
    int* bsum       = pos + N;
    int* perm       = bsum + 256;

    // ---- prep: convert + weights + degree histogram in one launch ----
    hipMemsetAsync(deg, 0, (size_t)N * sizeof(int), stream);
    const long nx = (long)N * NFEAT;
    const int nCvt = (int)((nx / 4 + 255) / 256);
    const int histB = (E + 255) / 256;
    prep<<<nCvt + 320 + histB, 256, 0, stream>>>(x, x_bf, nx, w1_l, w1_r, w2_l, w2_r, w_dec,
                                                 wc1, wc2, wdec, dst, deg, E, nCvt);

    // ---- CSR build (by dst), reused by both layers ----
    const int nb = (N + 1023) / 1024;            // must be <= 128 for scan_add's 2-load carry
    scan_blocks<<<nb, 256, 0, stream>>>(deg, row_off, bsum, N);
    scan_add<<<(N + 255) / 256, 256, 0, stream>>>(row_off, pos, bsum, N, E);
    fill_csr<<<histB, 256, 0, stream>>>(src, dst, pos, perm, E);

    const int gb = (N + 127) / 128;
    const int ggb = (N * 16 + 255) / 256;

    // ---- layer 1 ----
    gather_mean_bf<<<ggb, 256, 0, stream>>>(row_off, perm, x_bf, mean_bf, N);
    sage_mfma<true, false><<<gb, 256, 0, stream>>>(mean_bf, x_bf, wc1, b1_l,
                                                   nullptr, nullptr, nullptr, h1_bf, nullptr, N);

    // ---- layer 2 + fused decoder ----
    gather_mean_bf<<<ggb, 256, 0, stream>>>(row_off, perm, h1_bf, mean_bf, N);
    sage_mfma<false, true><<<gb, 256, 0, stream>>>(mean_bf, h1_bf, wc2, b2_l,
                                                   wdec, b_dec, h_out, nullptr, dxp, N);

    (void)n_in; (void)out_size; (void)ws_size;
}